// Round 8
// baseline (747.479 us; speedup 1.0000x reference)
//
#include <hip/hip_runtime.h>
#include <hip/hip_bf16.h>
#include <math.h>

#define IH 48
#define IW 48
#define LTOT 2304      // 48*48
#define CS 128
#define HS 96
#define KRED 1152      // 3*3*128
#define CRED 2048      // 4*4*128

typedef unsigned short u16;
typedef __attribute__((ext_vector_type(8))) short short8;
typedef __attribute__((ext_vector_type(8))) unsigned short ushort8;
typedef __attribute__((ext_vector_type(4))) float floatx4;

#define NS    ((size_t)LTOT*LTOT)     // 5,308,416
#define PLANE ((size_t)LTOT*KRED)     // 2,654,208
#define NRT   ((size_t)CRED*LTOT)     // 4,718,592

// ---- region layout (bytes), per batch slice ----
// APL/BPL (split planes) stay LIVE until k_refine.
// attb (10.6MB) + Rt (9.4MB) live in the old S2 region (21.2MB).
// Cc (18.9MB) overwrites S (dead after fusesoftmax).
#define OFF_APL  ((size_t)0)           // 2 bf16 planes, 10,616,832 B
#define OFF_BPL  ((size_t)10616832)    // 2 bf16 planes
#define OFF_S    ((size_t)21233664)    // NS fp32 (raw scores; alias: Cc)
#define OFF_S2   ((size_t)42467328)    // attb (NS u16) + Rt (NRT u16)
#define OFF_SM   ((size_t)63700992)    // ninv(2304 f32) + mmv(2304 f32)
#define OFF_CAND ((size_t)63719424)    // LTOT * 32 ints = 294,912 B
#define REGION   ((size_t)64014336)

__device__ __forceinline__ u16 f2bf(float v) {
    __hip_bfloat16 h = __float2bfloat16(v);
    return *reinterpret_cast<u16*>(&h);
}
__device__ __forceinline__ float bf2f(u16 b) {
    __hip_bfloat16 h = *reinterpret_cast<__hip_bfloat16*>(&b);
    return __bfloat162float(h);
}
__device__ __forceinline__ void split2(float v, u16& a, u16& b) {
    a = f2bf(v);
    b = f2bf(v - bf2f(a));
}

// ---------------- norm of W rows (gather-reduce) ----------------
__global__ __launch_bounds__(256) void k_wnorm(const float* __restrict__ b,
                                               float* __restrict__ ninvg,
                                               int b0, size_t zsF) {
    int bi = b0 + blockIdx.z;
    float* ninv = ninvg + (size_t)blockIdx.z * zsF;
    int l = blockIdx.x, t = threadIdx.x;
    __shared__ float red[256];
    float ss = 0.f;
    for (int G = t; G < KRED; G += 256) {
        int F = l * KRED + G;
        int p2 = F / LTOT, s = F - p2 * LTOT;
        int i = p2 / 384, j = (p2 / 128) % 3, c = p2 & 127;
        int u = s / IW + i - 1, v = s % IW + j - 1;
        if (u >= 0 && u < IH && v >= 0 && v < IW) {
            float w = b[(((size_t)bi * CS + c) * HS + 2 * u) * HS + 2 * v];
            ss += w * w;
        }
    }
    red[t] = ss; __syncthreads();
    for (int o = 128; o > 0; o >>= 1) { if (t < o) red[t] += red[t + o]; __syncthreads(); }
    if (t == 0) ninv[l] = 1.0f / fmaxf(sqrtf(red[0] + 1e-8f), 1e-4f);
}

// ---------------- merged gather: W (normalized, split) and Xp (split) ----------------
__global__ __launch_bounds__(256) void k_gather_ab(const float* __restrict__ b,
                                                   const float* __restrict__ f,
                                                   u16* __restrict__ Ag,
                                                   u16* __restrict__ Bg,
                                                   const float* __restrict__ ninvg,
                                                   int b0, size_t zsU, size_t zsF) {
    const unsigned half = (unsigned)(PLANE / 256);
    int bi = b0 + blockIdx.z;
    if (blockIdx.x < half) {
        u16* A = Ag + (size_t)blockIdx.z * zsU;
        const float* ninv = ninvg + (size_t)blockIdx.z * zsF;
        int idx = blockIdx.x * 256 + threadIdx.x;
        int p2 = idx / LTOT, s = idx - p2 * LTOT;
        int i = p2 / 384, j = (p2 / 128) % 3, c = p2 & 127;
        int u = s / IW + i - 1, v = s % IW + j - 1;
        float val = 0.f;
        if (u >= 0 && u < IH && v >= 0 && v < IW)
            val = b[(((size_t)bi * CS + c) * HS + 2 * u) * HS + 2 * v];
        val *= ninv[idx / KRED];
        u16 h1, h2; split2(val, h1, h2);
        A[idx] = h1; A[PLANE + idx] = h2;
    } else {
        u16* B = Bg + (size_t)blockIdx.z * zsU;
        int idx = (blockIdx.x - half) * 256 + threadIdx.x;
        int p = idx / KRED, G = idx - p * KRED;
        int y = p / IW, x = p % IW;
        int k1 = G / 384, k2 = (G / 128) % 3, c = G & 127;
        int u = y + k1 - 1, v = x + k2 - 1;
        float val = 0.f;
        if (u >= 0 && u < IH && v >= 0 && v < IW)
            val = f[(((size_t)bi * CS + c) * HS + 2 * u) * HS + 2 * v];
        u16 h1, h2; split2(val, h1, h2);
        B[idx] = h1; B[PLANE + idx] = h2;
    }
}

// ---------------- mask vector ----------------
__global__ __launch_bounds__(256) void k_mm(const float* __restrict__ mask,
                                            float* __restrict__ mmvg, int b0, size_t zsF) {
    int bi = b0 + blockIdx.z;
    float* out = mmvg + (size_t)blockIdx.z * zsF;
    int q = blockIdx.x * 256 + threadIdx.x;
    if (q >= LTOT) return;
    float ssum = 0.f;
    for (int t = 0; t < 9; t++) {
        int F = q * 9 + t;
        int pm = F / LTOT, s = F % LTOT;
        int i = pm / 3, j = pm % 3;
        int u = s / IW + i - 1, v = s % IW + j - 1;
        float val = 0.f;
        if (u >= 0 && u < IH && v >= 0 && v < IW)
            val = mask[((size_t)bi * HS + 2 * u) * HS + 2 * v];
        ssum += 1.0f - val;
    }
    out[q] = (ssum / 9.0f < 0.85f) ? 1.0f : 0.0f;
}

// ---------------- gather raw patches, pre-transposed: Rt[n][k] ----------------
__global__ __launch_bounds__(256) void k_gather_rt(const float* __restrict__ b,
                                                   u16* __restrict__ Rtg,
                                                   int b0, size_t zsU) {
    int bi = b0 + blockIdx.z;
    u16* Rt = Rtg + (size_t)blockIdx.z * zsU;
    size_t idx = (size_t)blockIdx.x * 256 + threadIdx.x;
    if (idx >= NRT) return;
    int n = (int)(idx / LTOT), k = (int)(idx - (size_t)n * LTOT);
    size_t F = (size_t)k * CRED + n;
    int pr = (int)(F / LTOT);
    int s = (int)(F - (size_t)pr * LTOT);
    int i = pr / 512, j = (pr / 128) & 3, c = pr & 127;
    int Y0 = 2 * (s / IW) + i - 1, X0 = 2 * (s % IW) + j - 1;
    float val = 0.f;
    if (Y0 >= 0 && Y0 < HS && X0 >= 0 && X0 < HS)
        val = b[(((size_t)bi * CS + c) * HS + Y0) * HS + X0];
    Rt[idx] = f2bf(val);
}

// ---------------- MFMA GEMM (NT): C[m,n] = sum_k A[m,k]*B[n,k] ----------------
// Proven structure: 128x128 tile, 4 waves (2x2), XOR LDS swizzle (0 conflicts),
// reg-staged, 2-barrier loop, bijective XCD swizzle. BK=128: 64 MFMA/iter.
template <int NP, int BK>
__global__ __launch_bounds__(256) void k_gemm_mfma(const u16* __restrict__ Ag,
                                                   const u16* __restrict__ Bg,
                                                   float* __restrict__ Cg,
                                                   size_t zsA, size_t zsB, size_t zsC,
                                                   size_t planeStride,
                                                   int M, int N, int K) {
    constexpr int SLOTS = BK / 8;
    constexpr int SMASK = SLOTS - 1;
    constexpr int TSZ = 128 * BK;
    constexpr int NLD = NP * BK / 16;
    __shared__ u16 lds[2 * NP * TSZ];
    u16* As = lds;
    u16* Bs = lds + NP * TSZ;
    const int tid = threadIdx.x;
    const int lane = tid & 63;
    const int wave = tid >> 6;
    const int wr = (wave >> 1) * 64, wc = (wave & 1) * 64;
    const int lrow = lane & 15, lq = lane >> 4;

    unsigned gx = gridDim.x, gy = gridDim.y;
    unsigned nwg = gx * gy * gridDim.z;
    unsigned wg = (blockIdx.z * gy + blockIdx.y) * gx + blockIdx.x;
    {
        unsigned q = nwg >> 3, r = nwg & 7, xcd = wg & 7, lid = wg >> 3;
        wg = (xcd < r ? xcd * (q + 1) : r * (q + 1) + (xcd - r) * q) + lid;
    }
    unsigned z = wg / (gx * gy);
    unsigned rem2 = wg - z * gx * gy;
    const int bm = (int)(rem2 / gx) * 128, bn = (int)(rem2 % gx) * 128;

    const u16* A = Ag + (size_t)z * zsA;
    const u16* B = Bg + (size_t)z * zsB;
    float* C = Cg + (size_t)z * zsC;

    floatx4 acc[4][4];
#pragma unroll
    for (int i = 0; i < 4; i++)
#pragma unroll
        for (int j = 0; j < 4; j++) acc[i][j] = (floatx4){0.f, 0.f, 0.f, 0.f};

    for (int kt = 0; kt < K; kt += BK) {
        ushort8 stA[NLD], stB[NLD];
#pragma unroll
        for (int e = 0; e < NLD; ++e) {
            int g = e * 256 + tid;
            int p = g / (128 * SLOTS);
            int gg = g % (128 * SLOTS);
            int row = gg / SLOTS, slot = gg & SMASK;
            stA[e] = *(const ushort8*)(A + (size_t)p * planeStride + (size_t)(bm + row) * K + kt + slot * 8);
            stB[e] = *(const ushort8*)(B + (size_t)p * planeStride + (size_t)(bn + row) * K + kt + slot * 8);
        }
        __syncthreads();
#pragma unroll
        for (int e = 0; e < NLD; ++e) {
            int g = e * 256 + tid;
            int p = g / (128 * SLOTS);
            int gg = g % (128 * SLOTS);
            int row = gg / SLOTS, slot = gg & SMASK;
            int dst = p * TSZ + row * BK + ((slot ^ (row & SMASK)) << 3);
            *(ushort8*)&As[dst] = stA[e];
            *(ushort8*)&Bs[dst] = stB[e];
        }
        __syncthreads();

#pragma unroll
        for (int ks = 0; ks < BK / 32; ++ks) {
            short8 af[NP][4];
#pragma unroll
            for (int p = 0; p < NP; ++p)
#pragma unroll
                for (int mi = 0; mi < 4; ++mi) {
                    int row = wr + mi * 16 + lrow;
                    af[p][mi] = *(const short8*)&As[p * TSZ + row * BK + ((((ks << 2) | lq) ^ (row & SMASK)) << 3)];
                }
#pragma unroll
            for (int ni = 0; ni < 4; ++ni) {
                short8 bfr[NP];
                int rowb = wc + ni * 16 + lrow;
                int bslot = ((((ks << 2) | lq) ^ (rowb & SMASK)) << 3);
#pragma unroll
                for (int p = 0; p < NP; ++p)
                    bfr[p] = *(const short8*)&Bs[p * TSZ + rowb * BK + bslot];
#pragma unroll
                for (int mi = 0; mi < 4; ++mi) {
                    if constexpr (NP == 1) {
                        acc[mi][ni] = __builtin_amdgcn_mfma_f32_16x16x32_bf16(af[0][mi], bfr[0], acc[mi][ni], 0, 0, 0);
                    } else {
                        acc[mi][ni] = __builtin_amdgcn_mfma_f32_16x16x32_bf16(af[1][mi], bfr[0], acc[mi][ni], 0, 0, 0);
                        acc[mi][ni] = __builtin_amdgcn_mfma_f32_16x16x32_bf16(af[0][mi], bfr[1], acc[mi][ni], 0, 0, 0);
                        acc[mi][ni] = __builtin_amdgcn_mfma_f32_16x16x32_bf16(af[0][mi], bfr[0], acc[mi][ni], 0, 0, 0);
                    }
                }
            }
        }
    }

    const int r0 = bm + wr + (lane >> 4) * 4;
    const int c0 = bn + wc + (lane & 15);
#pragma unroll
    for (int mi = 0; mi < 4; ++mi)
#pragma unroll
        for (int ni = 0; ni < 4; ++ni)
#pragma unroll
            for (int j = 0; j < 4; ++j)
                C[(size_t)(r0 + mi * 16 + j) * N + (c0 + ni * 16)] = acc[mi][ni][j];
}

// ---------------- fused fuse1+fuse2+softmax + candidate collection ----------------
__device__ __forceinline__ int permi(int a) { return (a % 48) * 48 + a / 48; }

__device__ __forceinline__ float f1_at(const float* __restrict__ S, int a, int b) {
    float s = S[(size_t)a * LTOT + b];
    if (a >= 1 && b >= 1) s += S[(size_t)(a - 1) * LTOT + (b - 1)];
    if (a < LTOT - 1 && b < LTOT - 1) s += S[(size_t)(a + 1) * LTOT + (b + 1)];
    return s;
}

__global__ __launch_bounds__(256) void k_fusesoftmax(const float* __restrict__ Sg,
                                                     const float* __restrict__ mmg,
                                                     u16* __restrict__ attbg,
                                                     int* __restrict__ candg,
                                                     size_t zsF, size_t zsU) {
    const float* S = Sg + (size_t)blockIdx.z * zsF;
    const float* mm = mmg + (size_t)blockIdx.z * zsF;
    u16* attb = attbg + (size_t)blockIdx.z * zsU;
    int* cand = candg + (size_t)blockIdx.z * zsF;   // int stride == float stride
    int l = blockIdx.x, t = threadIdx.x;
    __shared__ float red[256];
    __shared__ int scand[31];
    __shared__ int scnt;
    u16* arow = attb + (size_t)l * LTOT;

    const int At = permi(l);
    const int rm = (At >= 1) ? permi(At - 1) : -1;          // wave-uniform rows
    const int rp = (At < LTOT - 1) ? permi(At + 1) : -1;

    if (t == 0) scnt = 0;

    float v[9], m9[9];
#pragma unroll
    for (int i = 0; i < 9; ++i) {
        int p = t + 256 * i;
        float d = f1_at(S, l, p);
        int Bt = permi(p);
        if (rm >= 0 && Bt >= 1)        d += f1_at(S, rm, permi(Bt - 1));
        if (rp >= 0 && Bt < LTOT - 1)  d += f1_at(S, rp, permi(Bt + 1));
        m9[i] = mm[p];
        v[i] = d * m9[i] * 10.0f;
    }
    // global max (incl. masked zeros) for softmax
    float mx = -1e30f;
#pragma unroll
    for (int i = 0; i < 9; ++i) mx = fmaxf(mx, v[i]);
    red[t] = mx; __syncthreads();
    for (int o = 128; o > 0; o >>= 1) { if (t < o) red[t] = fmaxf(red[t], red[t + o]); __syncthreads(); }
    mx = red[0]; __syncthreads();
    float sm = 0.f;
#pragma unroll
    for (int i = 0; i < 9; ++i) sm += expf(v[i] - mx);
    red[t] = sm; __syncthreads();
    for (int o = 128; o > 0; o >>= 1) { if (t < o) red[t] += red[t + o]; __syncthreads(); }
    float Z = red[0]; __syncthreads();
    // unmasked max for candidate threshold
    float mul = -1e30f;
#pragma unroll
    for (int i = 0; i < 9; ++i) if (m9[i] > 0.f) mul = fmaxf(mul, v[i]);
    red[t] = mul; __syncthreads();
    for (int o = 128; o > 0; o >>= 1) { if (t < o) red[t] = fmaxf(red[t], red[t + o]); __syncthreads(); }
    float mu = red[0]; __syncthreads();
    // write att (bf16) + collect candidates within 4 logits of unmasked max
#pragma unroll
    for (int i = 0; i < 9; ++i) {
        int p = t + 256 * i;
        float e = expf(v[i] - mx);
        arow[p] = f2bf((e / Z) * m9[i]);
        if (m9[i] > 0.f && v[i] >= mu - 4.0f) {
            int pos = atomicAdd(&scnt, 1);
            if (pos < 31) scand[pos] = p;
        }
    }
    __syncthreads();
    int* cd = cand + l * 32;
    if (t == 0) cd[0] = scnt;
    if (t < 31 && t < scnt) cd[1 + t] = scand[t];
}

// ---------------- exact-argmax refinement (offsets) ----------------
// Recomputes the fused (fuse1+fuse2) score in fp32 from the split planes
// (w = hi+lo exactly reconstructs the normalized fp32 value to ~2^-17)
// for the collected candidates; first-index tie-break.
__device__ __forceinline__ int build_pairs(int l, int p, int* pa, int* pb) {
    int np = 0;
    int arr[3][2]; int na = 0;
    arr[na][0] = l; arr[na][1] = p; na++;
    int At = permi(l), Bt = permi(p);
    if (At >= 1 && Bt >= 1)               { arr[na][0] = permi(At - 1); arr[na][1] = permi(Bt - 1); na++; }
    if (At < LTOT - 1 && Bt < LTOT - 1)   { arr[na][0] = permi(At + 1); arr[na][1] = permi(Bt + 1); na++; }
    for (int s = 0; s < na; ++s) {
        int a = arr[s][0], b = arr[s][1];
        pa[np] = a; pb[np] = b; np++;
        if (a >= 1 && b >= 1)             { pa[np] = a - 1; pb[np] = b - 1; np++; }
        if (a < LTOT - 1 && b < LTOT - 1) { pa[np] = a + 1; pb[np] = b + 1; np++; }
    }
    return np;
}

__device__ __forceinline__ float exact_pair_part(const u16* __restrict__ A,
                                                 const u16* __restrict__ B,
                                                 int a, int b, int t, int stride) {
    const u16* wa = A + (size_t)a * KRED;
    const u16* wl = wa + PLANE;
    const u16* xb = B + (size_t)b * KRED;
    const u16* xl = xb + PLANE;
    float s = 0.f;
    for (int G = t; G < KRED; G += stride)
        s += (bf2f(wa[G]) + bf2f(wl[G])) * (bf2f(xb[G]) + bf2f(xl[G]));
    return s;
}

__global__ __launch_bounds__(256) void k_refine(const u16* __restrict__ Ag,
                                                const u16* __restrict__ Bg,
                                                const int* __restrict__ candg,
                                                const float* __restrict__ mmg,
                                                float* __restrict__ offout,
                                                int b0, size_t zsU, size_t zsF) {
    int z = blockIdx.z;
    int bi = b0 + z;
    const u16* A = Ag + (size_t)z * zsU;
    const u16* B = Bg + (size_t)z * zsU;
    const int* cd = candg + (size_t)z * zsF + (size_t)blockIdx.x * 32;
    int l = blockIdx.x, t = threadIdx.x;
    __shared__ float red[256];
    __shared__ int redi[256];
    int cnt = cd[0];
    int bestp = 0;

    if (cnt == 1) {
        bestp = cd[1];
    } else if (cnt > 1 && cnt <= 31) {
        float bv = -1e30f; int bp = 0x7fffffff;
        for (int ci = 0; ci < cnt; ++ci) {
            int p = cd[1 + ci];
            int pa[9], pb[9];
            int np = build_pairs(l, p, pa, pb);
            float s = 0.f;
            for (int s2 = 0; s2 < np; ++s2)
                s += exact_pair_part(A, B, pa[s2], pb[s2], t, 256);
            red[t] = s; __syncthreads();
            for (int o = 128; o > 0; o >>= 1) { if (t < o) red[t] += red[t + o]; __syncthreads(); }
            float tot = red[0]; __syncthreads();
            if (tot > bv || (tot == bv && p < bp)) { bv = tot; bp = p; }
        }
        bestp = bp;
    } else if (cnt > 31) {
        // fallback: exact scan of all unmasked columns (expected never on this data)
        const float* mm = mmg + (size_t)z * zsF;
        float bv = -1e30f; int bp = 0x7fffffff;
        for (int i = 0; i < 9; ++i) {
            int p = t + 256 * i;
            if (mm[p] <= 0.f) continue;
            int pa[9], pb[9];
            int np = build_pairs(l, p, pa, pb);
            float s = 0.f;
            for (int s2 = 0; s2 < np; ++s2)
                s += exact_pair_part(A, B, pa[s2], pb[s2], 0, 1);
            if (s > bv || (s == bv && p < bp)) { bv = s; bp = p; }
        }
        red[t] = bv; redi[t] = bp; __syncthreads();
        for (int o = 128; o > 0; o >>= 1) {
            if (t < o) {
                if (red[t + o] > red[t] || (red[t + o] == red[t] && redi[t + o] < redi[t])) {
                    red[t] = red[t + o]; redi[t] = redi[t + o];
                }
            }
            __syncthreads();
        }
        bestp = (red[0] <= -1e30f) ? 0 : redi[0];
    }
    if (t == 0) {
        int ly = l / IW, lx = l % IW;
        offout[((size_t)bi * 2 + 0) * LTOT + l] = (float)(bestp / 96 - ly);
        offout[((size_t)bi * 2 + 1) * LTOT + l] = (float)(bestp % 96 - lx);
    }
}

// ---------------- transposed-conv reduction ----------------
__global__ __launch_bounds__(256) void k_output(const float* __restrict__ Cg,
                                                float* __restrict__ yout,
                                                int b0, size_t zsF) {
    int bi = b0 + blockIdx.z;
    const float* C = Cg + (size_t)blockIdx.z * zsF;
    int idx = blockIdx.x * 256 + threadIdx.x;
    if (idx >= CS * HS * HS) return;
    int c = idx / (HS * HS), rem = idx % (HS * HS);
    int Y = rem / HS, X = rem % HS;
    float s = 0.f;
    int pu = (Y + 1) & 1, pv = (X + 1) & 1;
    for (int a = 0; a < 2; a++) {
        int u = pu + 2 * a;
        int ly2 = Y + 1 - u;
        if (ly2 < 0) continue;
        int ly = ly2 >> 1;
        if (ly >= IH) continue;
        for (int bb = 0; bb < 2; bb++) {
            int v = pv + 2 * bb;
            int lx2 = X + 1 - v;
            if (lx2 < 0) continue;
            int lx = lx2 >> 1;
            if (lx >= IW) continue;
            s += C[(size_t)(ly * IW + lx) * CRED + u * 512 + v * 128 + c];
        }
    }
    yout[(size_t)bi * CS * HS * HS + idx] = s * 0.25f;
}

// ---------------- launch ----------------
extern "C" void kernel_launch(void* const* d_in, const int* in_sizes, int n_in,
                              void* d_out, int out_size, void* d_ws, size_t ws_size,
                              hipStream_t stream) {
    const float* f = (const float*)d_in[0];
    const float* b = (const float*)d_in[1];
    const float* mask = (const float*)d_in[2];
    float* yout = (float*)d_out;
    float* offout = yout + (size_t)4 * CS * HS * HS;

    int ZB, nloop;
    if (ws_size >= 4 * REGION)      { ZB = 4; nloop = 1; }
    else if (ws_size >= 2 * REGION) { ZB = 2; nloop = 2; }
    else                            { ZB = 1; nloop = 4; }

    char* base = (char*)d_ws;
    u16*   Apl  = (u16*)(base + OFF_APL);
    u16*   Bpl  = (u16*)(base + OFF_BPL);
    float* S    = (float*)(base + OFF_S);
    u16*   attb = (u16*)(base + OFF_S2);
    u16*   Rt   = (u16*)(base + OFF_S2 + (size_t)10616832);
    float* Cc   = (float*)(base + OFF_S);    // alias: S dead after fusesoftmax
    float* ninv = (float*)(base + OFF_SM);
    float* mmv  = ninv + LTOT;
    int*   cand = (int*)(base + OFF_CAND);

    const size_t zsU = REGION / 2;   // per-z stride in u16 elements
    const size_t zsF = REGION / 4;   // per-z stride in float/int elements

    dim3 blk(256, 1, 1);
    const unsigned ghalf = (unsigned)(PLANE / 256);

    for (int it = 0; it < nloop; ++it) {
        int b0 = it * ZB;
        k_wnorm<<<dim3(LTOT, 1, ZB), blk, 0, stream>>>(b, ninv, b0, zsF);
        k_gather_ab<<<dim3(2 * ghalf, 1, ZB), blk, 0, stream>>>(b, f, Apl, Bpl, ninv, b0, zsU, zsF);
        k_mm<<<dim3((LTOT + 255) / 256, 1, ZB), blk, 0, stream>>>(mask, mmv, b0, zsF);
        // GEMM1: S[l,p] = Wn_hi . Xp_hi^T : M=N=2304, K=1152, plain bf16, BK=128
        k_gemm_mfma<1, 128><<<dim3(LTOT / 128, LTOT / 128, ZB), blk, 0, stream>>>(
            Apl, Bpl, S, zsU, zsU, zsF, PLANE, LTOT, LTOT, KRED);
        // fused fuse1+fuse2+softmax + candidate collection
        k_fusesoftmax<<<dim3(LTOT, 1, ZB), blk, 0, stream>>>(S, mmv, attb, cand, zsF, zsU);
        // exact argmax refinement -> offsets
        k_refine<<<dim3(LTOT, 1, ZB), blk, 0, stream>>>(Apl, Bpl, cand, mmv, offout, b0, zsU, zsF);
        k_gather_rt<<<dim3((unsigned)(NRT / 256), 1, ZB), blk, 0, stream>>>(b, Rt, b0, zsU);
        // GEMM2: C[l,G2] = att . Rt^T : M=2304, N=2048, K=2304, plain bf16, BK=128
        k_gemm_mfma<1, 128><<<dim3(CRED / 128, LTOT / 128, ZB), blk, 0, stream>>>(
            attb, Rt, Cc, zsU, zsU, zsF, PLANE, LTOT, CRED, LTOT);
        k_output<<<dim3((CS * HS * HS) / 256, 1, ZB), blk, 0, stream>>>(Cc, yout, b0, zsF);
    }
}

// Round 9
// 603.747 us; speedup vs baseline: 1.2381x; 1.2381x over previous
//
#include <hip/hip_runtime.h>
#include <hip/hip_bf16.h>
#include <math.h>

#define IH 48
#define IW 48
#define LTOT 2304      // 48*48
#define CS 128
#define HS 96
#define KRED 1152      // 3*3*128
#define CRED 2048      // 4*4*128

typedef unsigned short u16;
typedef __attribute__((ext_vector_type(8))) short short8;
typedef __attribute__((ext_vector_type(8))) unsigned short ushort8;
typedef __attribute__((ext_vector_type(4))) float floatx4;

#define NS    ((size_t)LTOT*LTOT)     // 5,308,416
#define PLANE ((size_t)LTOT*KRED)     // 2,654,208
#define NRT   ((size_t)CRED*LTOT)     // 4,718,592

// ---- region layout (bytes), per batch slice (aliased tight: 42.5MB) ----
// APL (w planes, 10.6MB)  -> alias attb (NS u16, 10.6MB) after gemm1
// BPL (x planes, 10.6MB)  -> alias Rt  (9.4MB)           after gemm1
// S   (NS fp32, 21.2MB)   -> alias Cc  (18.9MB)          after fusesoftmax
#define OFF_APL  ((size_t)0)
#define OFF_BPL  ((size_t)10616832)
#define OFF_S    ((size_t)21233664)
#define OFF_SM   ((size_t)42467328)    // ninv(2304 f32) + mmv(2304 f32)
#define REGION   ((size_t)42485760)

__device__ __forceinline__ u16 f2bf(float v) {
    __hip_bfloat16 h = __float2bfloat16(v);
    return *reinterpret_cast<u16*>(&h);
}
__device__ __forceinline__ float bf2f(u16 b) {
    __hip_bfloat16 h = *reinterpret_cast<__hip_bfloat16*>(&b);
    return __bfloat162float(h);
}
__device__ __forceinline__ void split2(float v, u16& a, u16& b) {
    a = f2bf(v);
    b = f2bf(v - bf2f(a));
}

// ---------------- norm of W rows (gather-reduce) ----------------
__global__ __launch_bounds__(256) void k_wnorm(const float* __restrict__ b,
                                               float* __restrict__ ninvg,
                                               int b0, size_t zsF) {
    int bi = b0 + blockIdx.z;
    float* ninv = ninvg + (size_t)blockIdx.z * zsF;
    int l = blockIdx.x, t = threadIdx.x;
    __shared__ float red[256];
    float ss = 0.f;
    for (int G = t; G < KRED; G += 256) {
        int F = l * KRED + G;
        int p2 = F / LTOT, s = F - p2 * LTOT;
        int i = p2 / 384, j = (p2 / 128) % 3, c = p2 & 127;
        int u = s / IW + i - 1, v = s % IW + j - 1;
        if (u >= 0 && u < IH && v >= 0 && v < IW) {
            float w = b[(((size_t)bi * CS + c) * HS + 2 * u) * HS + 2 * v];
            ss += w * w;
        }
    }
    red[t] = ss; __syncthreads();
    for (int o = 128; o > 0; o >>= 1) { if (t < o) red[t] += red[t + o]; __syncthreads(); }
    if (t == 0) ninv[l] = 1.0f / fmaxf(sqrtf(red[0] + 1e-8f), 1e-4f);
}

// ---------------- merged gather: W (normalized, split) and Xp (split) ----------------
__global__ __launch_bounds__(256) void k_gather_ab(const float* __restrict__ b,
                                                   const float* __restrict__ f,
                                                   u16* __restrict__ Ag,
                                                   u16* __restrict__ Bg,
                                                   const float* __restrict__ ninvg,
                                                   int b0, size_t zsU, size_t zsF) {
    const unsigned half = (unsigned)(PLANE / 256);
    int bi = b0 + blockIdx.z;
    if (blockIdx.x < half) {
        u16* A = Ag + (size_t)blockIdx.z * zsU;
        const float* ninv = ninvg + (size_t)blockIdx.z * zsF;
        int idx = blockIdx.x * 256 + threadIdx.x;
        int p2 = idx / LTOT, s = idx - p2 * LTOT;
        int i = p2 / 384, j = (p2 / 128) % 3, c = p2 & 127;
        int u = s / IW + i - 1, v = s % IW + j - 1;
        float val = 0.f;
        if (u >= 0 && u < IH && v >= 0 && v < IW)
            val = b[(((size_t)bi * CS + c) * HS + 2 * u) * HS + 2 * v];
        val *= ninv[idx / KRED];
        u16 h1, h2; split2(val, h1, h2);
        A[idx] = h1; A[PLANE + idx] = h2;
    } else {
        u16* B = Bg + (size_t)blockIdx.z * zsU;
        int idx = (blockIdx.x - half) * 256 + threadIdx.x;
        int p = idx / KRED, G = idx - p * KRED;
        int y = p / IW, x = p % IW;
        int k1 = G / 384, k2 = (G / 128) % 3, c = G & 127;
        int u = y + k1 - 1, v = x + k2 - 1;
        float val = 0.f;
        if (u >= 0 && u < IH && v >= 0 && v < IW)
            val = f[(((size_t)bi * CS + c) * HS + 2 * u) * HS + 2 * v];
        u16 h1, h2; split2(val, h1, h2);
        B[idx] = h1; B[PLANE + idx] = h2;
    }
}

// ---------------- mask vector ----------------
__global__ __launch_bounds__(256) void k_mm(const float* __restrict__ mask,
                                            float* __restrict__ mmvg, int b0, size_t zsF) {
    int bi = b0 + blockIdx.z;
    float* out = mmvg + (size_t)blockIdx.z * zsF;
    int q = blockIdx.x * 256 + threadIdx.x;
    if (q >= LTOT) return;
    float ssum = 0.f;
    for (int t = 0; t < 9; t++) {
        int F = q * 9 + t;
        int pm = F / LTOT, s = F % LTOT;
        int i = pm / 3, j = pm % 3;
        int u = s / IW + i - 1, v = s % IW + j - 1;
        float val = 0.f;
        if (u >= 0 && u < IH && v >= 0 && v < IW)
            val = mask[((size_t)bi * HS + 2 * u) * HS + 2 * v];
        ssum += 1.0f - val;
    }
    out[q] = (ssum / 9.0f < 0.85f) ? 1.0f : 0.0f;
}

// ---------------- gather raw patches, pre-transposed: Rt[n][k] ----------------
__global__ __launch_bounds__(256) void k_gather_rt(const float* __restrict__ b,
                                                   u16* __restrict__ Rtg,
                                                   int b0, size_t zsU) {
    int bi = b0 + blockIdx.z;
    u16* Rt = Rtg + (size_t)blockIdx.z * zsU;
    size_t idx = (size_t)blockIdx.x * 256 + threadIdx.x;
    if (idx >= NRT) return;
    int n = (int)(idx / LTOT), k = (int)(idx - (size_t)n * LTOT);
    size_t F = (size_t)k * CRED + n;
    int pr = (int)(F / LTOT);
    int s = (int)(F - (size_t)pr * LTOT);
    int i = pr / 512, j = (pr / 128) & 3, c = pr & 127;
    int Y0 = 2 * (s / IW) + i - 1, X0 = 2 * (s % IW) + j - 1;
    float val = 0.f;
    if (Y0 >= 0 && Y0 < HS && X0 >= 0 && X0 < HS)
        val = b[(((size_t)bi * CS + c) * HS + Y0) * HS + X0];
    Rt[idx] = f2bf(val);
}

// ---------------- MFMA GEMM (NT): C[m,n] = sum_k A[m,k]*B[n,k] ----------------
// Proven 2-barrier structure, now with 32KB LDS per block (4-5 blocks/CU):
// gemm1: NP=2/BK=32 (48 MFMA/wave/iter, 36 iters); gemm2: NP=1/BK=64 (32/iter, 36).
// XOR swizzle (slot ^ (row & SMASK)) is conflict-free at both BK (per-bank access
// count hits the hardware minimum). Bijective XCD swizzle over the full grid.
template <int NP, int BK>
__global__ __launch_bounds__(256) void k_gemm_mfma(const u16* __restrict__ Ag,
                                                   const u16* __restrict__ Bg,
                                                   float* __restrict__ Cg,
                                                   size_t zsA, size_t zsB, size_t zsC,
                                                   size_t planeStride,
                                                   int M, int N, int K) {
    constexpr int SLOTS = BK / 8;
    constexpr int SMASK = SLOTS - 1;
    constexpr int TSZ = 128 * BK;
    constexpr int NLD = NP * BK / 16;
    __shared__ u16 lds[2 * NP * TSZ];
    u16* As = lds;
    u16* Bs = lds + NP * TSZ;
    const int tid = threadIdx.x;
    const int lane = tid & 63;
    const int wave = tid >> 6;
    const int wr = (wave >> 1) * 64, wc = (wave & 1) * 64;
    const int lrow = lane & 15, lq = lane >> 4;

    unsigned gx = gridDim.x, gy = gridDim.y;
    unsigned nwg = gx * gy * gridDim.z;
    unsigned wg = (blockIdx.z * gy + blockIdx.y) * gx + blockIdx.x;
    {
        unsigned q = nwg >> 3, r = nwg & 7, xcd = wg & 7, lid = wg >> 3;
        wg = (xcd < r ? xcd * (q + 1) : r * (q + 1) + (xcd - r) * q) + lid;
    }
    unsigned z = wg / (gx * gy);
    unsigned rem2 = wg - z * gx * gy;
    const int bm = (int)(rem2 / gx) * 128, bn = (int)(rem2 % gx) * 128;

    const u16* A = Ag + (size_t)z * zsA;
    const u16* B = Bg + (size_t)z * zsB;
    float* C = Cg + (size_t)z * zsC;

    floatx4 acc[4][4];
#pragma unroll
    for (int i = 0; i < 4; i++)
#pragma unroll
        for (int j = 0; j < 4; j++) acc[i][j] = (floatx4){0.f, 0.f, 0.f, 0.f};

    for (int kt = 0; kt < K; kt += BK) {
        ushort8 stA[NLD], stB[NLD];
#pragma unroll
        for (int e = 0; e < NLD; ++e) {
            int g = e * 256 + tid;
            int p = g / (128 * SLOTS);
            int gg = g % (128 * SLOTS);
            int row = gg / SLOTS, slot = gg & SMASK;
            stA[e] = *(const ushort8*)(A + (size_t)p * planeStride + (size_t)(bm + row) * K + kt + slot * 8);
            stB[e] = *(const ushort8*)(B + (size_t)p * planeStride + (size_t)(bn + row) * K + kt + slot * 8);
        }
        __syncthreads();
#pragma unroll
        for (int e = 0; e < NLD; ++e) {
            int g = e * 256 + tid;
            int p = g / (128 * SLOTS);
            int gg = g % (128 * SLOTS);
            int row = gg / SLOTS, slot = gg & SMASK;
            int dst = p * TSZ + row * BK + ((slot ^ (row & SMASK)) << 3);
            *(ushort8*)&As[dst] = stA[e];
            *(ushort8*)&Bs[dst] = stB[e];
        }
        __syncthreads();

#pragma unroll
        for (int ks = 0; ks < BK / 32; ++ks) {
            short8 af[NP][4];
#pragma unroll
            for (int p = 0; p < NP; ++p)
#pragma unroll
                for (int mi = 0; mi < 4; ++mi) {
                    int row = wr + mi * 16 + lrow;
                    af[p][mi] = *(const short8*)&As[p * TSZ + row * BK + ((((ks << 2) | lq) ^ (row & SMASK)) << 3)];
                }
#pragma unroll
            for (int ni = 0; ni < 4; ++ni) {
                short8 bfr[NP];
                int rowb = wc + ni * 16 + lrow;
                int bslot = ((((ks << 2) | lq) ^ (rowb & SMASK)) << 3);
#pragma unroll
                for (int p = 0; p < NP; ++p)
                    bfr[p] = *(const short8*)&Bs[p * TSZ + rowb * BK + bslot];
#pragma unroll
                for (int mi = 0; mi < 4; ++mi) {
                    if constexpr (NP == 1) {
                        acc[mi][ni] = __builtin_amdgcn_mfma_f32_16x16x32_bf16(af[0][mi], bfr[0], acc[mi][ni], 0, 0, 0);
                    } else {
                        // small-first: lo*hi, hi*lo, hi*hi
                        acc[mi][ni] = __builtin_amdgcn_mfma_f32_16x16x32_bf16(af[1][mi], bfr[0], acc[mi][ni], 0, 0, 0);
                        acc[mi][ni] = __builtin_amdgcn_mfma_f32_16x16x32_bf16(af[0][mi], bfr[1], acc[mi][ni], 0, 0, 0);
                        acc[mi][ni] = __builtin_amdgcn_mfma_f32_16x16x32_bf16(af[0][mi], bfr[0], acc[mi][ni], 0, 0, 0);
                    }
                }
            }
        }
    }

    const int r0 = bm + wr + (lane >> 4) * 4;
    const int c0 = bn + wc + (lane & 15);
#pragma unroll
    for (int mi = 0; mi < 4; ++mi)
#pragma unroll
        for (int ni = 0; ni < 4; ++ni)
#pragma unroll
            for (int j = 0; j < 4; ++j)
                C[(size_t)(r0 + mi * 16 + j) * N + (c0 + ni * 16)] = acc[mi][ni][j];
}

// ---------------- fused fuse1+fuse2+softmax+argmax ----------------
__device__ __forceinline__ int permi(int a) { return (a % 48) * 48 + a / 48; }

__device__ __forceinline__ float f1_at(const float* __restrict__ S, int a, int b) {
    float s = S[(size_t)a * LTOT + b];
    if (a >= 1 && b >= 1) s += S[(size_t)(a - 1) * LTOT + (b - 1)];
    if (a < LTOT - 1 && b < LTOT - 1) s += S[(size_t)(a + 1) * LTOT + (b + 1)];
    return s;
}

__global__ __launch_bounds__(256) void k_fusesoftmax(const float* __restrict__ Sg,
                                                     const float* __restrict__ mmg,
                                                     u16* __restrict__ attbg,
                                                     float* __restrict__ offout,
                                                     int b0, size_t zsF, size_t zsU) {
    int bi = b0 + blockIdx.z;
    const float* S = Sg + (size_t)blockIdx.z * zsF;
    const float* mm = mmg + (size_t)blockIdx.z * zsF;
    u16* attb = attbg + (size_t)blockIdx.z * zsU;
    int l = blockIdx.x, t = threadIdx.x;
    __shared__ float red[256];
    __shared__ int redi[256];
    u16* arow = attb + (size_t)l * LTOT;

    const int At = permi(l);
    const int rm = (At >= 1) ? permi(At - 1) : -1;          // wave-uniform rows
    const int rp = (At < LTOT - 1) ? permi(At + 1) : -1;

    float v[9], m9[9];
#pragma unroll
    for (int i = 0; i < 9; ++i) {
        int p = t + 256 * i;
        float d = f1_at(S, l, p);
        int Bt = permi(p);
        if (rm >= 0 && Bt >= 1)        d += f1_at(S, rm, permi(Bt - 1));
        if (rp >= 0 && Bt < LTOT - 1)  d += f1_at(S, rp, permi(Bt + 1));
        m9[i] = mm[p];
        v[i] = d * m9[i] * 10.0f;
    }
    float mx = -1e30f;
#pragma unroll
    for (int i = 0; i < 9; ++i) mx = fmaxf(mx, v[i]);
    red[t] = mx; __syncthreads();
    for (int o = 128; o > 0; o >>= 1) { if (t < o) red[t] = fmaxf(red[t], red[t + o]); __syncthreads(); }
    mx = red[0]; __syncthreads();
    float sm = 0.f;
#pragma unroll
    for (int i = 0; i < 9; ++i) sm += expf(v[i] - mx);
    red[t] = sm; __syncthreads();
    for (int o = 128; o > 0; o >>= 1) { if (t < o) red[t] += red[t + o]; __syncthreads(); }
    float Z = red[0]; __syncthreads();
    float bv = -1.0f; int bidx2 = 0;
#pragma unroll
    for (int i = 0; i < 9; ++i) {
        int p = t + 256 * i;
        float e = expf(v[i] - mx);
        float a = (e / Z) * m9[i];
        arow[p] = f2bf(a);
        if (a > bv) { bv = a; bidx2 = p; }
    }
    red[t] = bv; redi[t] = bidx2; __syncthreads();
    for (int o = 128; o > 0; o >>= 1) {
        if (t < o) {
            if (red[t + o] > red[t] || (red[t + o] == red[t] && redi[t + o] < redi[t])) {
                red[t] = red[t + o]; redi[t] = redi[t + o];
            }
        }
        __syncthreads();
    }
    if (t == 0) {
        int off = redi[0];
        int ly = l / IW, lx = l % IW;
        offout[((size_t)bi * 2 + 0) * LTOT + l] = (float)(off / 96 - ly);
        offout[((size_t)bi * 2 + 1) * LTOT + l] = (float)(off % 96 - lx);
    }
}

// ---------------- transposed-conv reduction ----------------
__global__ __launch_bounds__(256) void k_output(const float* __restrict__ Cg,
                                                float* __restrict__ yout,
                                                int b0, size_t zsF) {
    int bi = b0 + blockIdx.z;
    const float* C = Cg + (size_t)blockIdx.z * zsF;
    int idx = blockIdx.x * 256 + threadIdx.x;
    if (idx >= CS * HS * HS) return;
    int c = idx / (HS * HS), rem = idx % (HS * HS);
    int Y = rem / HS, X = rem % HS;
    float s = 0.f;
    int pu = (Y + 1) & 1, pv = (X + 1) & 1;
    for (int a = 0; a < 2; a++) {
        int u = pu + 2 * a;
        int ly2 = Y + 1 - u;
        if (ly2 < 0) continue;
        int ly = ly2 >> 1;
        if (ly >= IH) continue;
        for (int bb = 0; bb < 2; bb++) {
            int v = pv + 2 * bb;
            int lx2 = X + 1 - v;
            if (lx2 < 0) continue;
            int lx = lx2 >> 1;
            if (lx >= IW) continue;
            s += C[(size_t)(ly * IW + lx) * CRED + u * 512 + v * 128 + c];
        }
    }
    yout[(size_t)bi * CS * HS * HS + idx] = s * 0.25f;
}

// ---------------- launch ----------------
extern "C" void kernel_launch(void* const* d_in, const int* in_sizes, int n_in,
                              void* d_out, int out_size, void* d_ws, size_t ws_size,
                              hipStream_t stream) {
    const float* f = (const float*)d_in[0];
    const float* b = (const float*)d_in[1];
    const float* mask = (const float*)d_in[2];
    float* yout = (float*)d_out;
    float* offout = yout + (size_t)4 * CS * HS * HS;

    int ZB, nloop;
    if (ws_size >= 4 * REGION)      { ZB = 4; nloop = 1; }
    else if (ws_size >= 2 * REGION) { ZB = 2; nloop = 2; }
    else                            { ZB = 1; nloop = 4; }

    char* base = (char*)d_ws;
    u16*   Apl  = (u16*)(base + OFF_APL);
    u16*   Bpl  = (u16*)(base + OFF_BPL);
    float* S    = (float*)(base + OFF_S);
    float* Cc   = (float*)(base + OFF_S);    // alias: S dead after fusesoftmax
    float* ninv = (float*)(base + OFF_SM);
    float* mmv  = ninv + LTOT;
    u16*   attb = Apl;   // alias (w planes dead after gemm1)
    u16*   Rt   = Bpl;   // alias (x planes dead after gemm1)

    const size_t zsU = REGION / 2;   // per-z stride in u16 elements
    const size_t zsF = REGION / 4;   // per-z stride in float elements

    dim3 blk(256, 1, 1);
    const unsigned ghalf = (unsigned)(PLANE / 256);

    for (int it = 0; it < nloop; ++it) {
        int b0 = it * ZB;
        k_wnorm<<<dim3(LTOT, 1, ZB), blk, 0, stream>>>(b, ninv, b0, zsF);
        k_gather_ab<<<dim3(2 * ghalf, 1, ZB), blk, 0, stream>>>(b, f, Apl, Bpl, ninv, b0, zsU, zsF);
        k_mm<<<dim3((LTOT + 255) / 256, 1, ZB), blk, 0, stream>>>(mask, mmv, b0, zsF);
        // GEMM1: S[l,p] = Wn . Xp^T : M=N=2304, K=1152, split-2, 3 products, BK=32 (32KB LDS)
        k_gemm_mfma<2, 32><<<dim3(LTOT / 128, LTOT / 128, ZB), blk, 0, stream>>>(
            Apl, Bpl, S, zsU, zsU, zsF, PLANE, LTOT, LTOT, KRED);
        // fused fuse1+fuse2+softmax+argmax
        k_fusesoftmax<<<dim3(LTOT, 1, ZB), blk, 0, stream>>>(S, mmv, attb, offout, b0, zsF, zsU);
        k_gather_rt<<<dim3((unsigned)(NRT / 256), 1, ZB), blk, 0, stream>>>(b, Rt, b0, zsU);
        // GEMM2: C[l,G2] = att . Rt^T : M=2304, N=2048, K=2304, plain bf16, BK=64 (32KB LDS)
        k_gemm_mfma<1, 64><<<dim3(CRED / 128, LTOT / 128, ZB), blk, 0, stream>>>(
            attb, Rt, Cc, zsU, zsU, zsF, PLANE, LTOT, CRED, LTOT);
        k_output<<<dim3((CS * HS * HS) / 256, 1, ZB), blk, 0, stream>>>(Cc, yout, b0, zsF);
    }
}

// Round 10
// 512.410 us; speedup vs baseline: 1.4588x; 1.1783x over previous
//
#include <hip/hip_runtime.h>
#include <hip/hip_bf16.h>
#include <math.h>

#define IH 48
#define IW 48
#define LTOT 2304      // 48*48
#define CS 128
#define HS 96
#define KRED 1152      // 3*3*128
#define CRED 2048      // 4*4*128

typedef unsigned short u16;
typedef __attribute__((ext_vector_type(8))) short short8;
typedef __attribute__((ext_vector_type(8))) unsigned short ushort8;
typedef __attribute__((ext_vector_type(4))) float floatx4;

#define NS    ((size_t)LTOT*LTOT)     // 5,308,416
#define PLANE ((size_t)LTOT*KRED)     // 2,654,208
#define NRT   ((size_t)CRED*LTOT)     // 4,718,592

// ---- region layout (bytes), per batch slice (42.5MB; ZB=4 fits in ~170MB) ----
#define OFF_APL  ((size_t)0)
#define OFF_BPL  ((size_t)10616832)
#define OFF_S    ((size_t)21233664)
#define OFF_SM   ((size_t)42467328)    // ninv(2304 f32) + mmv(2304 f32)
#define REGION   ((size_t)42485760)

__device__ __forceinline__ u16 f2bf(float v) {
    __hip_bfloat16 h = __float2bfloat16(v);
    return *reinterpret_cast<u16*>(&h);
}
__device__ __forceinline__ float bf2f(u16 b) {
    __hip_bfloat16 h = *reinterpret_cast<__hip_bfloat16*>(&b);
    return __bfloat162float(h);
}
__device__ __forceinline__ void split2(float v, u16& a, u16& b) {
    a = f2bf(v);
    b = f2bf(v - bf2f(a));
}

// ---------------- norm of W rows (gather-reduce) ----------------
__global__ __launch_bounds__(256) void k_wnorm(const float* __restrict__ b,
                                               float* __restrict__ ninvg,
                                               int b0, size_t zsF) {
    int bi = b0 + blockIdx.z;
    float* ninv = ninvg + (size_t)blockIdx.z * zsF;
    int l = blockIdx.x, t = threadIdx.x;
    __shared__ float red[256];
    float ss = 0.f;
    for (int G = t; G < KRED; G += 256) {
        int F = l * KRED + G;
        int p2 = F / LTOT, s = F - p2 * LTOT;
        int i = p2 / 384, j = (p2 / 128) % 3, c = p2 & 127;
        int u = s / IW + i - 1, v = s % IW + j - 1;
        if (u >= 0 && u < IH && v >= 0 && v < IW) {
            float w = b[(((size_t)bi * CS + c) * HS + 2 * u) * HS + 2 * v];
            ss += w * w;
        }
    }
    red[t] = ss; __syncthreads();
    for (int o = 128; o > 0; o >>= 1) { if (t < o) red[t] += red[t + o]; __syncthreads(); }
    if (t == 0) ninv[l] = 1.0f / fmaxf(sqrtf(red[0] + 1e-8f), 1e-4f);
}

// ---------------- gather W (normalized, split) — reads already row-coalesced ----------------
__global__ __launch_bounds__(256) void k_gather_w(const float* __restrict__ b,
                                                  u16* __restrict__ Ag,
                                                  const float* __restrict__ ninvg,
                                                  int b0, size_t zsU, size_t zsF) {
    int bi = b0 + blockIdx.z;
    u16* A = Ag + (size_t)blockIdx.z * zsU;
    const float* ninv = ninvg + (size_t)blockIdx.z * zsF;
    int idx = blockIdx.x * 256 + threadIdx.x;
    int p2 = idx / LTOT, s = idx - p2 * LTOT;
    int i = p2 / 384, j = (p2 / 128) % 3, c = p2 & 127;
    int u = s / IW + i - 1, v = s % IW + j - 1;
    float val = 0.f;
    if (u >= 0 && u < IH && v >= 0 && v < IW)
        val = b[(((size_t)bi * CS + c) * HS + 2 * u) * HS + 2 * v];
    val *= ninv[idx / KRED];
    u16 h1, h2; split2(val, h1, h2);
    A[idx] = h1; A[PLANE + idx] = h2;
}

// ---------------- gather Xp (split) — LDS-tiled: f reads x-inner coalesced ----------------
// Block: one y-row, 16 x positions, all G=1152. Stage fd[c][u in y-1..y+1][v in x0-1..x0+16]
// (128*3*18 floats) coalesced, then emit in G-order (writes coalesced) from LDS.
__global__ __launch_bounds__(256) void k_gather_x_tiled(const float* __restrict__ f,
                                                        u16* __restrict__ Bg,
                                                        int b0, size_t zsU) {
    __shared__ float ldsf[128 * 55];   // [c][3][18] padded 54->55 (bank-spread)
    int bi = b0 + blockIdx.z;
    u16* B = Bg + (size_t)blockIdx.z * zsU;
    int bx = blockIdx.x;
    int y = bx / 3, x0 = (bx % 3) * 16;
    int t = threadIdx.x;
    // phase1: 128*54 = 6912 source values, 27 per thread
    for (int i = 0; i < 27; ++i) {
        int g = i * 256 + t;
        if (g < 6912) {
            int vl = g % 18;
            int row = (g / 18) % 3;
            int c = g / 54;
            int u = y + row - 1;
            int v = x0 - 1 + vl;
            float val = 0.f;
            if (u >= 0 && u < IH && v >= 0 && v < IW)
                val = f[(((size_t)bi * CS + c) * HS + 2 * u) * HS + 2 * v];
            ldsf[c * 55 + row * 18 + vl] = val;
        }
    }
    __syncthreads();
    // phase2: 16*1152 = 18432 outputs, 72 per thread
    for (int i = 0; i < 72; ++i) {
        int o = i * 256 + t;
        int xp = o / 1152, G = o - xp * 1152;
        int k1 = G / 384, k2 = (G >> 7) % 3, c = G & 127;
        float val = ldsf[c * 55 + k1 * 18 + xp + k2];
        u16 h1, h2; split2(val, h1, h2);
        size_t idx = (size_t)(y * IW + x0 + xp) * KRED + G;
        B[idx] = h1; B[PLANE + idx] = h2;
    }
}

// ---------------- mask vector ----------------
__global__ __launch_bounds__(256) void k_mm(const float* __restrict__ mask,
                                            float* __restrict__ mmvg, int b0, size_t zsF) {
    int bi = b0 + blockIdx.z;
    float* out = mmvg + (size_t)blockIdx.z * zsF;
    int q = blockIdx.x * 256 + threadIdx.x;
    if (q >= LTOT) return;
    float ssum = 0.f;
    for (int t = 0; t < 9; t++) {
        int F = q * 9 + t;
        int pm = F / LTOT, s = F % LTOT;
        int i = pm / 3, j = pm % 3;
        int u = s / IW + i - 1, v = s % IW + j - 1;
        float val = 0.f;
        if (u >= 0 && u < IH && v >= 0 && v < IW)
            val = mask[((size_t)bi * HS + 2 * u) * HS + 2 * v];
        ssum += 1.0f - val;
    }
    out[q] = (ssum / 9.0f < 0.85f) ? 1.0f : 0.0f;
}

// ---------------- gather raw patches pre-transposed, LDS-tiled transpose ----------------
// Rt[n][k] = R[k][n], R[k][n] = g(F = k*2048+n) (scrambled gather from b).
// Read R in k-major (F consecutive -> source coalesced), transpose 64x64 in LDS,
// write Rt rows coalesced.
__global__ __launch_bounds__(256) void k_gather_rt_tiled(const float* __restrict__ b,
                                                         u16* __restrict__ Rtg,
                                                         int b0, size_t zsU) {
    __shared__ u16 tile[64 * 65];
    int bi = b0 + blockIdx.z;
    u16* Rt = Rtg + (size_t)blockIdx.z * zsU;
    int bx = blockIdx.x;
    int k0 = (bx >> 5) * 64, n0 = (bx & 31) * 64;
    int t = threadIdx.x;
    // phase1: read 64k x 64n, F-consecutive per lane-run
    for (int i = 0; i < 16; ++i) {
        int kl = i * 4 + (t >> 6), nl = t & 63;
        int F = (k0 + kl) * CRED + n0 + nl;
        int pr = F / LTOT, s = F - pr * LTOT;
        int ii = pr / 512, j = (pr >> 7) & 3, c = pr & 127;
        int Y0 = 2 * (s / IW) + ii - 1, X0 = 2 * (s % IW) + j - 1;
        float val = 0.f;
        if (Y0 >= 0 && Y0 < HS && X0 >= 0 && X0 < HS)
            val = b[(((size_t)bi * CS + c) * HS + Y0) * HS + X0];
        tile[kl * 65 + nl] = f2bf(val);
    }
    __syncthreads();
    // phase2: write Rt[n0+nl][k0+kl], k-inner coalesced
    for (int i = 0; i < 16; ++i) {
        int nl = i * 4 + (t >> 6), kl = t & 63;
        Rt[(size_t)(n0 + nl) * LTOT + k0 + kl] = tile[kl * 65 + nl];
    }
}

// ---------------- MFMA GEMM (NT): C[m,n] = sum_k A[m,k]*B[n,k] ----------------
// Proven 2-barrier structure (round 7): 128x128 tile, 4 waves, XOR LDS swizzle
// (0 conflicts at SLOTS>=8), reg-staged, bijective XCD swizzle.
// gemm1: NP=2/BK=64 (96 MFMA/wave/iter); gemm2: NP=1/BK=128 (64/iter).
template <int NP, int BK>
__global__ __launch_bounds__(256) void k_gemm_mfma(const u16* __restrict__ Ag,
                                                   const u16* __restrict__ Bg,
                                                   float* __restrict__ Cg,
                                                   size_t zsA, size_t zsB, size_t zsC,
                                                   size_t planeStride,
                                                   int M, int N, int K) {
    constexpr int SLOTS = BK / 8;
    constexpr int SMASK = SLOTS - 1;
    constexpr int TSZ = 128 * BK;
    constexpr int NLD = NP * BK / 16;
    __shared__ u16 lds[2 * NP * TSZ];
    u16* As = lds;
    u16* Bs = lds + NP * TSZ;
    const int tid = threadIdx.x;
    const int lane = tid & 63;
    const int wave = tid >> 6;
    const int wr = (wave >> 1) * 64, wc = (wave & 1) * 64;
    const int lrow = lane & 15, lq = lane >> 4;

    unsigned gx = gridDim.x, gy = gridDim.y;
    unsigned nwg = gx * gy * gridDim.z;
    unsigned wg = (blockIdx.z * gy + blockIdx.y) * gx + blockIdx.x;
    {
        unsigned q = nwg >> 3, r = nwg & 7, xcd = wg & 7, lid = wg >> 3;
        wg = (xcd < r ? xcd * (q + 1) : r * (q + 1) + (xcd - r) * q) + lid;
    }
    unsigned z = wg / (gx * gy);
    unsigned rem2 = wg - z * gx * gy;
    const int bm = (int)(rem2 / gx) * 128, bn = (int)(rem2 % gx) * 128;

    const u16* A = Ag + (size_t)z * zsA;
    const u16* B = Bg + (size_t)z * zsB;
    float* C = Cg + (size_t)z * zsC;

    floatx4 acc[4][4];
#pragma unroll
    for (int i = 0; i < 4; i++)
#pragma unroll
        for (int j = 0; j < 4; j++) acc[i][j] = (floatx4){0.f, 0.f, 0.f, 0.f};

    for (int kt = 0; kt < K; kt += BK) {
        ushort8 stA[NLD], stB[NLD];
#pragma unroll
        for (int e = 0; e < NLD; ++e) {
            int g = e * 256 + tid;
            int p = g / (128 * SLOTS);
            int gg = g % (128 * SLOTS);
            int row = gg / SLOTS, slot = gg & SMASK;
            stA[e] = *(const ushort8*)(A + (size_t)p * planeStride + (size_t)(bm + row) * K + kt + slot * 8);
            stB[e] = *(const ushort8*)(B + (size_t)p * planeStride + (size_t)(bn + row) * K + kt + slot * 8);
        }
        __syncthreads();
#pragma unroll
        for (int e = 0; e < NLD; ++e) {
            int g = e * 256 + tid;
            int p = g / (128 * SLOTS);
            int gg = g % (128 * SLOTS);
            int row = gg / SLOTS, slot = gg & SMASK;
            int dst = p * TSZ + row * BK + ((slot ^ (row & SMASK)) << 3);
            *(ushort8*)&As[dst] = stA[e];
            *(ushort8*)&Bs[dst] = stB[e];
        }
        __syncthreads();

#pragma unroll
        for (int ks = 0; ks < BK / 32; ++ks) {
            short8 af[NP][4];
#pragma unroll
            for (int p = 0; p < NP; ++p)
#pragma unroll
                for (int mi = 0; mi < 4; ++mi) {
                    int row = wr + mi * 16 + lrow;
                    af[p][mi] = *(const short8*)&As[p * TSZ + row * BK + ((((ks << 2) | lq) ^ (row & SMASK)) << 3)];
                }
#pragma unroll
            for (int ni = 0; ni < 4; ++ni) {
                short8 bfr[NP];
                int rowb = wc + ni * 16 + lrow;
                int bslot = ((((ks << 2) | lq) ^ (rowb & SMASK)) << 3);
#pragma unroll
                for (int p = 0; p < NP; ++p)
                    bfr[p] = *(const short8*)&Bs[p * TSZ + rowb * BK + bslot];
#pragma unroll
                for (int mi = 0; mi < 4; ++mi) {
                    if constexpr (NP == 1) {
                        acc[mi][ni] = __builtin_amdgcn_mfma_f32_16x16x32_bf16(af[0][mi], bfr[0], acc[mi][ni], 0, 0, 0);
                    } else {
                        // small-first: lo*hi, hi*lo, hi*hi
                        acc[mi][ni] = __builtin_amdgcn_mfma_f32_16x16x32_bf16(af[1][mi], bfr[0], acc[mi][ni], 0, 0, 0);
                        acc[mi][ni] = __builtin_amdgcn_mfma_f32_16x16x32_bf16(af[0][mi], bfr[1], acc[mi][ni], 0, 0, 0);
                        acc[mi][ni] = __builtin_amdgcn_mfma_f32_16x16x32_bf16(af[0][mi], bfr[0], acc[mi][ni], 0, 0, 0);
                    }
                }
            }
        }
    }

    const int r0 = bm + wr + (lane >> 4) * 4;
    const int c0 = bn + wc + (lane & 15);
#pragma unroll
    for (int mi = 0; mi < 4; ++mi)
#pragma unroll
        for (int ni = 0; ni < 4; ++ni)
#pragma unroll
            for (int j = 0; j < 4; ++j)
                C[(size_t)(r0 + mi * 16 + j) * N + (c0 + ni * 16)] = acc[mi][ni][j];
}

// ---------------- fused fuse1+fuse2+softmax+argmax ----------------
__device__ __forceinline__ int permi(int a) { return (a % 48) * 48 + a / 48; }

__device__ __forceinline__ float f1_at(const float* __restrict__ S, int a, int b) {
    float s = S[(size_t)a * LTOT + b];
    if (a >= 1 && b >= 1) s += S[(size_t)(a - 1) * LTOT + (b - 1)];
    if (a < LTOT - 1 && b < LTOT - 1) s += S[(size_t)(a + 1) * LTOT + (b + 1)];
    return s;
}

__global__ __launch_bounds__(256) void k_fusesoftmax(const float* __restrict__ Sg,
                                                     const float* __restrict__ mmg,
                                                     u16* __restrict__ attbg,
                                                     float* __restrict__ offout,
                                                     int b0, size_t zsF, size_t zsU) {
    int bi = b0 + blockIdx.z;
    const float* S = Sg + (size_t)blockIdx.z * zsF;
    const float* mm = mmg + (size_t)blockIdx.z * zsF;
    u16* attb = attbg + (size_t)blockIdx.z * zsU;
    // XCD-chunk: blocks with same bx%8 share an XCD; give each XCD a contiguous
    // l-range so the 9 shared S-rows (l±1, l±47..49) are L2-local.
    int bx = blockIdx.x;
    int l = (bx & 7) * 288 + (bx >> 3);
    int t = threadIdx.x;
    __shared__ float red[256];
    __shared__ int redi[256];
    u16* arow = attb + (size_t)l * LTOT;

    const int At = permi(l);
    const int rm = (At >= 1) ? permi(At - 1) : -1;          // wave-uniform rows
    const int rp = (At < LTOT - 1) ? permi(At + 1) : -1;

    float v[9], m9[9];
#pragma unroll
    for (int i = 0; i < 9; ++i) {
        int p = t + 256 * i;
        float d = f1_at(S, l, p);
        int Bt = permi(p);
        if (rm >= 0 && Bt >= 1)        d += f1_at(S, rm, permi(Bt - 1));
        if (rp >= 0 && Bt < LTOT - 1)  d += f1_at(S, rp, permi(Bt + 1));
        m9[i] = mm[p];
        v[i] = d * m9[i] * 10.0f;
    }
    float mx = -1e30f;
#pragma unroll
    for (int i = 0; i < 9; ++i) mx = fmaxf(mx, v[i]);
    red[t] = mx; __syncthreads();
    for (int o = 128; o > 0; o >>= 1) { if (t < o) red[t] = fmaxf(red[t], red[t + o]); __syncthreads(); }
    mx = red[0]; __syncthreads();
    float sm = 0.f;
#pragma unroll
    for (int i = 0; i < 9; ++i) sm += expf(v[i] - mx);
    red[t] = sm; __syncthreads();
    for (int o = 128; o > 0; o >>= 1) { if (t < o) red[t] += red[t + o]; __syncthreads(); }
    float Z = red[0]; __syncthreads();
    float bv = -1.0f; int bidx2 = 0;
#pragma unroll
    for (int i = 0; i < 9; ++i) {
        int p = t + 256 * i;
        float e = expf(v[i] - mx);
        float a = (e / Z) * m9[i];
        arow[p] = f2bf(a);
        if (a > bv) { bv = a; bidx2 = p; }
    }
    red[t] = bv; redi[t] = bidx2; __syncthreads();
    for (int o = 128; o > 0; o >>= 1) {
        if (t < o) {
            if (red[t + o] > red[t] || (red[t + o] == red[t] && redi[t + o] < redi[t])) {
                red[t] = red[t + o]; redi[t] = redi[t + o];
            }
        }
        __syncthreads();
    }
    if (t == 0) {
        int off = redi[0];
        int ly = l / IW, lx = l % IW;
        offout[((size_t)bi * 2 + 0) * LTOT + l] = (float)(off / 96 - ly);
        offout[((size_t)bi * 2 + 1) * LTOT + l] = (float)(off % 96 - lx);
    }
}

// ---------------- transposed-conv reduction, LDS-tiled ----------------
// Block: tile Y0..Y0+3 x X0..X0+15 x all c. Phase1 reads C with c-inner
// (512B coalesced runs), LDS-transpose [pos][c] (pad 129), phase2 writes yout
// with (Y,X)-inner coalesced per fixed c.
__global__ __launch_bounds__(256) void k_output_tiled(const float* __restrict__ Cg,
                                                      float* __restrict__ yout,
                                                      int b0, size_t zsF) {
    __shared__ float lo[64 * 129];
    int bi = b0 + blockIdx.z;
    const float* C = Cg + (size_t)blockIdx.z * zsF;
    int bx = blockIdx.x;
    int Y0 = (bx / 6) * 4, X0 = (bx % 6) * 16;
    int t = threadIdx.x;
    int c = t & 127;
    // phase1
    for (int i = 0; i < 32; ++i) {
        int pos = i * 2 + (t >> 7);
        int Y = Y0 + (pos >> 4), X = X0 + (pos & 15);
        float s = 0.f;
        int pu = (Y + 1) & 1, pv = (X + 1) & 1;
#pragma unroll
        for (int a = 0; a < 2; a++) {
            int u = pu + 2 * a;
            int ly2 = Y + 1 - u;
            if (ly2 < 0) continue;
            int ly = ly2 >> 1;
            if (ly >= IH) continue;
#pragma unroll
            for (int bb = 0; bb < 2; bb++) {
                int v = pv + 2 * bb;
                int lx2 = X + 1 - v;
                if (lx2 < 0) continue;
                int lx = lx2 >> 1;
                if (lx >= IW) continue;
                s += C[(size_t)(ly * IW + lx) * CRED + u * 512 + v * 128 + c];
            }
        }
        lo[pos * 129 + c] = s * 0.25f;
    }
    __syncthreads();
    // phase2
    for (int i = 0; i < 32; ++i) {
        int cc = i * 4 + (t >> 6);
        int pos = t & 63;
        float val = lo[pos * 129 + cc];
        int yl = pos >> 4, xl = pos & 15;
        yout[(((size_t)bi * CS + cc) * HS + Y0 + yl) * HS + X0 + xl] = val;
    }
}

// ---------------- launch ----------------
extern "C" void kernel_launch(void* const* d_in, const int* in_sizes, int n_in,
                              void* d_out, int out_size, void* d_ws, size_t ws_size,
                              hipStream_t stream) {
    const float* f = (const float*)d_in[0];
    const float* b = (const float*)d_in[1];
    const float* mask = (const float*)d_in[2];
    float* yout = (float*)d_out;
    float* offout = yout + (size_t)4 * CS * HS * HS;

    int ZB, nloop;
    if (ws_size >= 4 * REGION)      { ZB = 4; nloop = 1; }
    else if (ws_size >= 2 * REGION) { ZB = 2; nloop = 2; }
    else                            { ZB = 1; nloop = 4; }

    char* base = (char*)d_ws;
    u16*   Apl  = (u16*)(base + OFF_APL);
    u16*   Bpl  = (u16*)(base + OFF_BPL);
    float* S    = (float*)(base + OFF_S);
    float* Cc   = (float*)(base + OFF_S);    // alias: S dead after fusesoftmax
    float* ninv = (float*)(base + OFF_SM);
    float* mmv  = ninv + LTOT;
    u16*   attb = Apl;   // alias (w planes dead after gemm1)
    u16*   Rt   = Bpl;   // alias (x planes dead after gemm1)

    const size_t zsU = REGION / 2;   // per-z stride in u16 elements
    const size_t zsF = REGION / 4;   // per-z stride in float elements

    dim3 blk(256, 1, 1);
    const unsigned ghalf = (unsigned)(PLANE / 256);

    for (int it = 0; it < nloop; ++it) {
        int b0 = it * ZB;
        k_wnorm<<<dim3(LTOT, 1, ZB), blk, 0, stream>>>(b, ninv, b0, zsF);
        k_gather_w<<<dim3(ghalf, 1, ZB), blk, 0, stream>>>(b, Apl, ninv, b0, zsU, zsF);
        k_gather_x_tiled<<<dim3(IH * 3, 1, ZB), blk, 0, stream>>>(f, Bpl, b0, zsU);
        k_mm<<<dim3((LTOT + 255) / 256, 1, ZB), blk, 0, stream>>>(mask, mmv, b0, zsF);
        // GEMM1: S[l,p] = Wn . Xp^T : M=N=2304, K=1152, split-2, 3 products, BK=64
        k_gemm_mfma<2, 64><<<dim3(LTOT / 128, LTOT / 128, ZB), blk, 0, stream>>>(
            Apl, Bpl, S, zsU, zsU, zsF, PLANE, LTOT, LTOT, KRED);
        // fused fuse1+fuse2+softmax+argmax (XCD-chunked)
        k_fusesoftmax<<<dim3(LTOT, 1, ZB), blk, 0, stream>>>(S, mmv, attb, offout, b0, zsF, zsU);
        // Rt via coalesced gather + LDS transpose
        k_gather_rt_tiled<<<dim3((LTOT / 64) * (CRED / 64), 1, ZB), blk, 0, stream>>>(b, Rt, b0, zsU);
        // GEMM2: C[l,G2] = att . Rt^T : M=2304, N=2048, K=2304, plain bf16, BK=128
        k_gemm_mfma<1, 128><<<dim3(CRED / 128, LTOT / 128, ZB), blk, 0, stream>>>(
            attb, Rt, Cc, zsU, zsU, zsF, PLANE, LTOT, CRED, LTOT);
        // y via LDS-tiled transpose (coalesced C reads AND yout writes)
        k_output_tiled<<<dim3((HS / 4) * (HS / 16), 1, ZB), blk, 0, stream>>>(Cc, yout, b0, zsF);
    }
}